// Round 11
// baseline (169.828 us; speedup 1.0000x reference)
//
#include <hip/hip_runtime.h>
#include <math.h>

#define NB 16
#define TT 800
#define FF 90
#define SS 128
#define LL 200
#define NEGV (-1e30f)

#define DNODES 16    // den nodes per utterance
#define DNDRX 50     // den frames per node (16*50 = 800)
#define QNODES 32    // num nodes per utterance
#define QDRX 25      // num frames per node
#define BROW 26      // band diagonals (QDRX+1)
#define BST 28       // Bd row stride in halves (56B, 8B-aligned)
#define NEGH (-60000.0f)
#define EPAD 228     // padded num emission row (200 + 26 + slack)
#define LN2F 0.69314718055994531f
#define LOG2E 1.4426950408889634f

typedef __attribute__((ext_vector_type(8))) short short8;
typedef __attribute__((ext_vector_type(16))) float f32x16;
typedef _Float16 h4 __attribute__((ext_vector_type(4)));
typedef unsigned uint2v __attribute__((ext_vector_type(2)));

static __device__ __forceinline__ unsigned short f2bf(float x) {
    union { float f; unsigned u; } v; v.f = x;
    unsigned r = (v.u + 0x7FFFu + ((v.u >> 16) & 1u)) >> 16;
    return (unsigned short)r;
}
// truncating bf16 pair pack in ONE VALU op (v_perm_b32), non-negative values
static __device__ __forceinline__ unsigned packperm(float a, float b) {
    return __builtin_amdgcn_perm(__float_as_uint(b), __float_as_uint(a),
                                 0x07060302u);
}

// ======================= Kernel A (r9-validated, 91us, absmax 0) ============
// 768 blocks x 256 threads. Dens (blocks 0..255) dispatch first.
//   den block (1 node, 4 waves x 32 rows): X register-resident; 32x32x16
//       MFMA; C-frag -> next B-frag via permlane32_swap. Zero LDS in t-loop.
//   num block (1 node, 256 thr): column-parallel band, triangle-cut.
__global__ __launch_bounds__(256, 2) void mmi_nodes(
    const float* __restrict__ x,
    const int*   __restrict__ sup,
    const float* __restrict__ trans,
    const int*   __restrict__ den_labels,
    const int*   __restrict__ num_labels,
    unsigned*    __restrict__ Pout,     // [NB*DNODES][8192] u32 (bf16 pairs)
    float*       __restrict__ scales4,  // [NB*DNODES][4] pow2 exps per wave
    _Float16*    __restrict__ Bd)       // [NB*QNODES][201][BST]
{
    __shared__ __align__(16) unsigned char SMEM[45632];
    const int tid = threadIdx.x;

    if (blockIdx.x < NB * DNODES) {
        // ---------------- den node product (register-resident X) -----------
        const int bid = blockIdx.x;
        const int u  = bid >> 4;
        const int nd = bid & 15;
        const int t0 = nd * DNDRX;
        const int nf = sup[u * 3 + 2];
        unsigned* Pg = Pout + (size_t)bid * 8192;

        if (t0 >= nf) {   // frozen node -> identity
            #pragma unroll
            for (int k2 = 0; k2 < 32; ++k2) {
                const int ww = tid + k2 * 256;
                const int row = ww >> 6, colw = ww & 63;
                unsigned val = 0;
                if (row == 2 * colw)     val |= 0x3F80u;
                if (row == 2 * colw + 1) val |= 0x3F800000u;
                Pg[ww] = val;
            }
            if (tid < 4) scales4[bid * 4 + tid] = 0.0f;
            return;
        }

        const int w = tid >> 6, l = tid & 63;
        const int l31 = l & 31, h = l >> 5;
        const int row = w * 32 + l31;        // this lane's X row

        unsigned* AFs   = (unsigned*)SMEM;            // 8192 u32 = 32 KB
        unsigned* ptabP = (unsigned*)(SMEM + 32768);  // 50*64 u32 = 12.8 KB

        // ---- stage A = E^T fragments (32x32x16 layout) through LDS ----
        #pragma unroll
        for (int i = 0; i < 32; ++i) {
            const int wi = tid + i * 256;             // 0..8191
            const int f  = wi >> 2, j2 = wi & 3;
            const int fl = f & 63, kc = (f >> 6) & 7, mt = f >> 9;
            const int col = mt * 32 + (fl & 31);
            const int krow = kc * 16 + (fl >> 5) * 8 + 2 * j2;
            const float a = __expf(trans[(krow    ) * SS + col]);
            const float b = __expf(trans[(krow + 1) * SS + col]);
            AFs[wi] = (unsigned)f2bf(a) | ((unsigned)f2bf(b) << 16);
        }
        // ---- stage emissions: packed bf16 pairs, half-permuted layout ----
        for (int idx = tid; idx < DNDRX * 64; idx += 256) {
            const int k = idx >> 6, within = idx & 63;
            const int h2 = within >> 5, rem = within & 31;
            const int mt = rem >> 3, r2 = (rem >> 1) & 3, b = rem & 1;
            const int cp = 16 * mt + 4 * r2 + 2 * h2 + b;
            const int fr = min(t0 + k, TT - 1);
            const float* xr = x + ((size_t)u * TT + fr) * FF;
            const float ea = __expf(xr[den_labels[2 * cp]]);
            const float eb = __expf(xr[den_labels[2 * cp + 1]]);
            ptabP[idx] = (unsigned)f2bf(ea) | ((unsigned)f2bf(eb) << 16);
        }
        __syncthreads();

        short8 afrag[4][8];
        #pragma unroll
        for (int mt = 0; mt < 4; ++mt)
            #pragma unroll
            for (int kc = 0; kc < 8; ++kc)
                afrag[mt][kc] =
                    *(const short8*)(AFs + ((mt * 8 + kc) * 64 + l) * 4);

        // ---- init X0 = exp(T) * p0 directly into C-fragment registers ----
        f32x16 acc[4];
        #pragma unroll
        for (int mt = 0; mt < 4; ++mt) {
            #pragma unroll
            for (int r2 = 0; r2 < 4; ++r2)
                #pragma unroll
                for (int b = 0; b < 2; ++b) {
                    const float2 t2 = ((const float2*)(trans + (size_t)row * SS +
                                        mt * 32 + 8 * r2 + 4 * h))[b];
                    const unsigned pp = ptabP[h * 32 + mt * 8 + r2 * 2 + b];
                    const float p0 = __uint_as_float(pp << 16);
                    const float p1 = __uint_as_float(pp & 0xFFFF0000u);
                    acc[mt][4 * r2 + 2 * b]     = __expf(t2.x) * p0;
                    acc[mt][4 * r2 + 2 * b + 1] = __expf(t2.y) * p1;
                }
        }

        const int kmax = min(DNDRX, nf - t0);
        int eacc = 0;
        float redmax = 1.0f;

        for (int k = 1; k < kmax; ++k) {
            const bool dosc = ((k & 3) == 0);
            float sc = 1.0f;
            if (dosc) {
                const float mm = fmaxf(redmax, 1e-37f);
                const int e = (int)((__float_as_uint(mm) >> 23) & 255u);
                sc = __uint_as_float((unsigned)(254 - e) << 23);
                eacc += (e - 127);
            }

            // pack X_k (pair p covers acc regs 2p, 2p+1)
            unsigned pk[4][8];
            #pragma unroll
            for (int mt = 0; mt < 4; ++mt)
                #pragma unroll
                for (int p = 0; p < 8; ++p)
                    pk[mt][p] = packperm(acc[mt][2 * p], acc[mt][2 * p + 1]);

            #pragma unroll
            for (int mt = 0; mt < 4; ++mt) {
                f32x16 z = {0.f, 0.f, 0.f, 0.f, 0.f, 0.f, 0.f, 0.f,
                            0.f, 0.f, 0.f, 0.f, 0.f, 0.f, 0.f, 0.f};
                acc[mt] = z;
            }

            // X_{k+1} = X_k * E: B-frag per kc built with 2 permlane32_swap
            #pragma unroll
            for (int kc = 0; kc < 8; ++kc) {
                const int s = kc & 1, mk = kc >> 1;
                const uint2v s1 = __builtin_amdgcn_permlane32_swap(
                    pk[mk][4 * s], pk[mk][4 * s + 2], false, false);
                const uint2v s2 = __builtin_amdgcn_permlane32_swap(
                    pk[mk][4 * s + 1], pk[mk][4 * s + 3], false, false);
                union { unsigned u[4]; short8 s8; } B;
                B.u[0] = s1[0]; B.u[1] = s2[0]; B.u[2] = s1[1]; B.u[3] = s2[1];
                #pragma unroll
                for (int mt = 0; mt < 4; ++mt)
                    acc[mt] = __builtin_amdgcn_mfma_f32_32x32x16_bf16(
                        afrag[mt][kc], B.s8, acc[mt], 0, 0, 0);
            }

            // emission (broadcast b128 reads; layout matches acc reg order)
            const bool dmax = ((k & 3) == 3);
            float vmax = 0.0f;
            const unsigned* pcb = ptabP + k * 64 + h * 32;
            #pragma unroll
            for (int mt = 0; mt < 4; ++mt) {
                #pragma unroll
                for (int half2 = 0; half2 < 2; ++half2) {
                    const uint4 pu = *(const uint4*)(pcb + mt * 8 + 4 * half2);
                    #pragma unroll
                    for (int j = 0; j < 4; ++j) {
                        const unsigned pw = (j == 0) ? pu.x : (j == 1) ? pu.y
                                          : (j == 2) ? pu.z : pu.w;
                        float f0 = __uint_as_float(pw << 16);
                        float f1 = __uint_as_float(pw & 0xFFFF0000u);
                        if (dosc) { f0 *= sc; f1 *= sc; }
                        const int r0 = half2 * 8 + 2 * j;
                        acc[mt][r0]     *= f0;
                        acc[mt][r0 + 1] *= f1;
                        if (dmax)
                            vmax = fmaxf(vmax,
                                fmaxf(acc[mt][r0], acc[mt][r0 + 1]));
                    }
                }
            }
            if (dmax) {
                #pragma unroll
                for (int off = 32; off >= 1; off >>= 1)
                    vmax = fmaxf(vmax, __shfl_xor(vmax, off, 64));
                redmax = vmax;
            }
        }

        // ---- epilogue: bounce through LDS for coalesced Pout write ----
        unsigned* Xo = (unsigned*)SMEM;   // reuse AFs region (32 KB)
        #pragma unroll
        for (int mt = 0; mt < 4; ++mt)
            #pragma unroll
            for (int p = 0; p < 8; ++p) {
                const int cp = 16 * mt + 4 * (p >> 1) + 2 * h + (p & 1);
                Xo[row * 64 + cp] = packperm(acc[mt][2 * p], acc[mt][2 * p + 1]);
            }
        __syncthreads();
        #pragma unroll
        for (int i = 0; i < 32; ++i) {
            const int ww = tid + i * 256;
            Pg[ww] = Xo[ww];
        }
        if (l == 0) scales4[bid * 4 + w] = (float)eacc;
        return;
    }

    // ---------------- num band product: ONE node, column-parallel -----------
    {
        float* est = (float*)SMEM;                 // [25][EPAD] f32 = 22.8 KB

        const int slot = blockIdx.x - NB * DNODES;   // 0..511
        const int u    = slot >> 5;
        const int nd   = slot & 31;
        const int nf   = sup[u * 3 + 2];
        const int* nlu = num_labels + u * LL;

        for (int idx = tid; idx < QDRX * EPAD; idx += 256) {
            const int tt  = idx / EPAD;
            const int j   = idx - tt * EPAD;
            const int jj  = min(j, 199);
            const int fr  = min(nd * QDRX + tt, TT - 1);
            est[idx] = x[((size_t)u * TT + fr) * FF + nlu[jj]] * LOG2E;
        }
        __syncthreads();

        const int c  = tid;            // band source column (row r = c + d)
        const int t0 = nd * QDRX;
        const int kmaxg = min(QDRX, max(nf - t0, 0));

        float a[BROW];
        a[0] = 0.0f;
        #pragma unroll
        for (int d = 1; d < BROW; ++d) a[d] = NEGV;

        const float* etc = est + (c - 1);
        for (int t = 0; t < kmaxg; ++t, etc += EPAD) {
            const int tc = t + 1;   // wave-uniform live-band bound
            #pragma unroll
            for (int d = BROW - 1; d >= 1; --d) {
                if (d <= tc) {
                    const float e  = etc[d];    // emission of row c+d
                    const float aa = a[d], bb = a[d - 1];
                    const float mx = fmaxf(aa, bb);
                    const float dd = fminf(aa, bb) - mx;
                    a[d] = e + mx +
                           __builtin_amdgcn_logf(
                               1.0f + __builtin_amdgcn_exp2f(dd));
                }
            }
            a[0] = (c == 0) ? NEGV : (etc[0] + a[0]);
        }

        if (c <= 200) {
            _Float16* Bg = Bd + (size_t)slot * 201 * BST;
            #pragma unroll
            for (int d = 0; d < BROW; ++d) {
                const int r = c + d;
                if (r <= 200) Bg[r * BST + d] = (_Float16)fmaxf(a[d], NEGH);
            }
            if (c < BROW - 1) {   // fill k > r triangle (unreachable transfers)
                for (int kk = c + 1; kk < BROW; ++kk)
                    Bg[c * BST + kk] = (_Float16)NEGH;
            }
        }
    }
}

// ======================= Kernel B: chains + fused finalize ==================
// r9-validated structure; den chain prefetch deepened 1 -> 2 (r7-validated
// pattern family): load of node i+2 issues before node i's compute, hiding
// one full HBM/L2 latency per iteration.
__global__ __launch_bounds__(256) void mmi_chain(
    const unsigned short* __restrict__ Pmat,   // [16][DNODES][128*128] bf16
    const _Float16* __restrict__ Bd,           // [16][QNODES][201][BST]
    const float* __restrict__ scales4,         // [16*DNODES][4]
    const int* __restrict__ num_lens,
    const int* __restrict__ sup,
    float* __restrict__ dsc,                   // [0..15] den, [16..31] num
    unsigned* __restrict__ ctr,                // completion counter (modulo)
    float* __restrict__ out)
{
    __shared__ float sh_v[SS];
    __shared__ float sh_part[8 * SS];
    __shared__ float sh_red[2];
    __shared__ float ab[2][232];
    __shared__ int sfl;

    const int tid = threadIdx.x;

    if (blockIdx.x < NB) {
        const int u = blockIdx.x;
        const int gg = tid & 31, c = tid >> 5;
        const unsigned short* Pu = Pmat + (size_t)u * DNODES * 16384;

        if (tid < SS) sh_v[tid] = (tid == 0) ? 1.0f : 0.0f;
        int   e2acc = 0;
        float sscal = 0.0f;

        uint2 c0[16], c1[16], c2[16];
        #pragma unroll
        for (int j = 0; j < 16; ++j)
            c0[j] = *(const uint2*)(Pu + (16 * c + j) * SS + 4 * gg);
        #pragma unroll
        for (int j = 0; j < 16; ++j)
            c1[j] = *(const uint2*)(Pu + 16384 + (16 * c + j) * SS + 4 * gg);
        __syncthreads();

        for (int i = 0; i < DNODES; ++i) {
            if (i + 2 < DNODES) {
                const unsigned short* Pn = Pu + (size_t)(i + 2) * 16384;
                #pragma unroll
                for (int j = 0; j < 16; ++j)
                    c2[j] = *(const uint2*)(Pn + (16 * c + j) * SS + 4 * gg);
            }
            // per-32-row-group pow2 scales of this node
            const float* s4 = scales4 + (size_t)(u * DNODES + i) * 4;
            const float gmax = fmaxf(fmaxf(s4[0], s4[1]), fmaxf(s4[2], s4[3]));
            const float fgr = __builtin_amdgcn_exp2f(s4[c >> 1] - gmax);
            sscal += gmax;

            const float4* av = (const float4*)(sh_v + 16 * c);
            float4 aa[4] = {av[0], av[1], av[2], av[3]};
            const float* as = (const float*)aa;
            float4 acc = make_float4(0.f, 0.f, 0.f, 0.f);
            #pragma unroll
            for (int j = 0; j < 16; ++j) {
                const float e0 = __uint_as_float(c0[j].x << 16);
                const float e1 = __uint_as_float(c0[j].x & 0xFFFF0000u);
                const float e2 = __uint_as_float(c0[j].y << 16);
                const float e3 = __uint_as_float(c0[j].y & 0xFFFF0000u);
                acc.x = fmaf(as[j], e0, acc.x);
                acc.y = fmaf(as[j], e1, acc.y);
                acc.z = fmaf(as[j], e2, acc.z);
                acc.w = fmaf(as[j], e3, acc.w);
            }
            acc.x *= fgr; acc.y *= fgr; acc.z *= fgr; acc.w *= fgr;
            *(float4*)(sh_part + c * SS + 4 * gg) = acc;
            __syncthreads();

            float v = 0.0f;
            if (tid < SS) {
                float y = 0.0f;
                #pragma unroll
                for (int cc = 0; cc < 8; ++cc) y += sh_part[cc * SS + tid];
                v = y;
                float m = v;
                #pragma unroll
                for (int off = 32; off >= 1; off >>= 1)
                    m = fmaxf(m, __shfl_xor(m, off, 64));
                if ((tid & 63) == 0) sh_red[tid >> 6] = m;
            }
            __syncthreads();
            if (tid < SS) {
                const float mm = fmaxf(fmaxf(sh_red[0], sh_red[1]), 1e-37f);
                const int e = (int)((__float_as_uint(mm) >> 23) & 255u);
                const float inv = __uint_as_float((unsigned)(254 - e) << 23);
                e2acc += (e - 127);
                sh_v[tid] = v * inv;
            }
            #pragma unroll
            for (int j = 0; j < 16; ++j) { c0[j] = c1[j]; c1[j] = c2[j]; }
            __syncthreads();
        }

        if (tid < SS) {
            float s = sh_v[tid];
            #pragma unroll
            for (int off = 32; off >= 1; off >>= 1)
                s += __shfl_xor(s, off, 64);
            if ((tid & 63) == 0) sh_red[tid >> 6] = s;
        }
        __syncthreads();
        if (tid == 0)
            atomicExch(&dsc[u], LN2F * ((float)e2acc + sscal) +
                                __logf(sh_red[0] + sh_red[1]));
    } else {
        // ---------------- num chain: band matvecs (r9-validated) ----------
        const int u = blockIdx.x - NB;
        const _Float16* Bu = Bd + (size_t)u * QNODES * 201 * BST;
        const int r = tid;
        const bool act = (r < 201);

        if (r < 232) { ab[0][r] = NEGV; ab[1][r] = NEGV; }
        h4 nx1[7], nx2[7];
        float dv[BROW];
        if (act) {
            const h4* s0 = (const h4*)(Bu + (size_t)r * BST);
            #pragma unroll
            for (int t7 = 0; t7 < 7; ++t7) nx1[t7] = s0[t7];
            #pragma unroll
            for (int k = 0; k < BROW; ++k) dv[k] = (float)nx1[k >> 2][k & 3];
            const h4* s1 = (const h4*)(Bu + ((size_t)201 + r) * BST);
            #pragma unroll
            for (int t7 = 0; t7 < 7; ++t7) nx1[t7] = s1[t7];
        }
        __syncthreads();
        if (r == 0) ab[0][QDRX] = 0.0f;    // alpha[0] = 0 (log2), offset QDRX
        __syncthreads();

        int cur = 0;
        for (int nd = 0; nd < QNODES; ++nd) {
            if (nd + 2 < QNODES && act) {
                const h4* src = (const h4*)(Bu + ((size_t)(nd + 2) * 201 + r) * BST);
                #pragma unroll
                for (int t7 = 0; t7 < 7; ++t7) nx2[t7] = src[t7];
            }
            float anew = NEGV;
            if (act) {
                float tr[BROW];
                #pragma unroll
                for (int k = 0; k < BROW; ++k)
                    tr[k] = dv[k] + ab[cur][QDRX + r - k];
                float m = tr[0];
                #pragma unroll
                for (int k = 1; k < BROW; ++k) m = fmaxf(m, tr[k]);
                float s = 0.0f;
                #pragma unroll
                for (int k = 0; k < BROW; ++k)
                    s += __builtin_amdgcn_exp2f(tr[k] - m);
                anew = m + __builtin_amdgcn_logf(s);
            }
            if (act) ab[cur ^ 1][QDRX + r] = anew;
            cur ^= 1;
            __syncthreads();
            if (act) {
                #pragma unroll
                for (int k = 0; k < BROW; ++k) dv[k] = (float)nx1[k >> 2][k & 3];
                #pragma unroll
                for (int t7 = 0; t7 < 7; ++t7) nx1[t7] = nx2[t7];
            }
        }
        if (r == 0)
            atomicExch(&dsc[NB + u], ab[cur][QDRX + num_lens[u]] * LN2F);
    }

    // ---------------- fused finalize: last chain block ----------------
    __threadfence();
    if (tid == 0) sfl = ((atomicAdd(ctr, 1u) & 31u) == 31u);
    __syncthreads();
    if (!sfl) return;
    __threadfence();
    if (tid < 64) {
        float tot_score = 0.0f, tot_frames = 0.0f, all_frames = 0.0f;
        if (tid < NB) {
            const float d = atomicAdd(&dsc[tid], 0.0f);       // coherent read
            const float n = atomicAdd(&dsc[NB + tid], 0.0f);
            const float tot = n - d;
            const int nf = sup[tid * 3 + 2];
            const bool fin = isfinite(tot) && (tot > 0.5f * NEGV);
            tot_score  = fin ? tot : 0.0f;
            tot_frames = fin ? (float)nf : 0.0f;
            all_frames = (float)nf;
        }
        #pragma unroll
        for (int off = 32; off >= 1; off >>= 1) {
            tot_score  += __shfl_xor(tot_score, off, 64);
            tot_frames += __shfl_xor(tot_frames, off, 64);
            all_frames += __shfl_xor(all_frames, off, 64);
        }
        if (tid == 0) {
            out[0] = tot_score;
            out[1] = tot_frames;
            out[2] = all_frames;
        }
    }
}

// ======================= Finalize (fallback path only) ======================
__global__ void mmi_finalize(const float* __restrict__ sc,
                             const int* __restrict__ sup,
                             float* __restrict__ out)
{
    const int tid = threadIdx.x;
    float tot_score = 0.0f, tot_frames = 0.0f, all_frames = 0.0f;
    if (tid < NB) {
        const float tot = sc[NB + tid] - sc[tid];
        const int nf = sup[tid * 3 + 2];
        const bool fin = isfinite(tot) && (tot > 0.5f * NEGV);
        tot_score  = fin ? tot : 0.0f;
        tot_frames = fin ? (float)nf : 0.0f;
        all_frames = (float)nf;
    }
    #pragma unroll
    for (int off = 32; off >= 1; off >>= 1) {
        tot_score  += __shfl_xor(tot_score, off, 64);
        tot_frames += __shfl_xor(tot_frames, off, 64);
        all_frames += __shfl_xor(all_frames, off, 64);
    }
    if (tid == 0) {
        out[0] = tot_score;
        out[1] = tot_frames;
        out[2] = all_frames;
    }
}

// ======================= Fallback (validated round-4 kernel) =================
#define XBF (16 * FF)
__global__ __launch_bounds__(256) void mmi_forward_fb(
    const float* __restrict__ x, const int* __restrict__ sup,
    const float* __restrict__ trans, const int* __restrict__ den_labels,
    const int* __restrict__ num_labels, const int* __restrict__ num_lens,
    float* __restrict__ ws)
{
    const int tid = threadIdx.x;
    if (blockIdx.x < NB) {
        __shared__ float sh_v[SS];
        __shared__ float sh_part[8 * SS];
        __shared__ float sh_red[4];
        __shared__ __align__(16) float xbuf[2][XBF];
        const int n = blockIdx.x, nf = sup[n * 3 + 2];
        const int g = tid & 31, c = tid >> 5;
        float4 e[16];
        #pragma unroll
        for (int j = 0; j < 16; ++j) {
            const float4 t4 = *(const float4*)(trans + (size_t)(16 * c + j) * SS + 4 * g);
            e[j] = make_float4(__expf(t4.x), __expf(t4.y), __expf(t4.z), __expf(t4.w));
        }
        const int lab = (tid < SS) ? den_labels[tid & (SS - 1)] : 0;
        const float* xb = x + (size_t)n * TT * FF;
        {
            const float4* s0 = (const float4*)xb;
            float4 p0 = s0[tid]; float4 p1; if (tid < 104) p1 = s0[256 + tid];
            float4* d0 = (float4*)xbuf[0];
            d0[tid] = p0; if (tid < 104) d0[256 + tid] = p1;
        }
        if (tid < SS) sh_v[tid] = (tid == 0) ? 1.0f : 0.0f;
        float logM = 0.0f, v = 0.0f, pe = 0.0f;
        float4 pf0, pf1;
        __syncthreads();
        for (int t = 0; t < nf; ++t) {
            const int b = t >> 4;
            if (tid < SS) pe = __expf(xbuf[b & 1][(t & 15) * FF + lab]);
            float4 aa[4];
            { const float4* av = (const float4*)(sh_v + 16 * c);
              aa[0] = av[0]; aa[1] = av[1]; aa[2] = av[2]; aa[3] = av[3]; }
            const float* as = (const float*)aa;
            float4 acc = make_float4(0.f, 0.f, 0.f, 0.f);
            #pragma unroll
            for (int j = 0; j < 16; ++j) {
                acc.x = fmaf(as[j], e[j].x, acc.x); acc.y = fmaf(as[j], e[j].y, acc.y);
                acc.z = fmaf(as[j], e[j].z, acc.z); acc.w = fmaf(as[j], e[j].w, acc.w);
            }
            *(float4*)(sh_part + c * SS + 4 * g) = acc;
            if ((t & 15) == 8) {
                const int tn = (b + 1) * 16;
                if (tn < nf) {
                    const float4* s = (const float4*)(xb + (size_t)tn * FF);
                    pf0 = s[tid]; if (tid < 104) pf1 = s[256 + tid];
                }
            }
            __syncthreads();
            const bool rs = ((t & 15) == 15);
            if (tid < SS) {
                float y = 0.0f;
                #pragma unroll
                for (int cc = 0; cc < 8; ++cc) y += sh_part[cc * SS + tid];
                v = y * pe;
                if (rs) {
                    float m = v;
                    #pragma unroll
                    for (int off = 32; off >= 1; off >>= 1)
                        m = fmaxf(m, __shfl_xor(m, off, 64));
                    if ((tid & 63) == 0) sh_red[tid >> 6] = m;
                }
            }
            if (rs) {
                const int tn = (b + 1) * 16;
                if (tn < nf) {
                    float4* dst = (float4*)xbuf[(b + 1) & 1];
                    dst[tid] = pf0; if (tid < 104) dst[256 + tid] = pf1;
                }
                __syncthreads();
                if (tid < SS) {
                    float mm = fmaxf(fmaxf(sh_red[0], sh_red[1]), 1e-37f);
                    v *= (1.0f / mm); logM += __logf(mm);
                }
            }
            if (tid < SS) sh_v[tid] = v;
            __syncthreads();
        }
        if (tid < SS) {
            float ssum = v;
            #pragma unroll
            for (int off = 32; off >= 1; off >>= 1) ssum += __shfl_xor(ssum, off, 64);
            if ((tid & 63) == 0) sh_red[2 + (tid >> 6)] = ssum;
        }
        __syncthreads();
        if (tid == 0) ws[n] = logM + __logf(sh_red[2] + sh_red[3]);
    } else {
        const int w = tid >> 6, l = tid & 63;
        const int n = (blockIdx.x - NB) * 4 + w;
        const int nf = sup[n * 3 + 2];
        const float* xb = x + (size_t)n * TT * FF;
        const int* nl = num_labels + n * LL;
        int li[4];
        #pragma unroll
        for (int k = 0; k < 4; ++k) li[k] = nl[min(4 * l + k, LL - 1)];
        float a4[4] = {NEGV, NEGV, NEGV, NEGV};
        float ea[4], eb[4];
        #pragma unroll
        for (int k = 0; k < 4; ++k) ea[k] = xb[li[k]];
        { const float* xr = xb + (size_t)min(1, nf - 1) * FF;
          #pragma unroll
          for (int k = 0; k < 4; ++k) eb[k] = xr[li[k]]; }
        auto step = [&](float (&ee)[4], int t) {
            float left = __shfl_up(a4[3], 1, 64);
            if (l == 0) left = (t == 0) ? 0.0f : NEGV;
            float prev = left;
            #pragma unroll
            for (int k = 0; k < 4; ++k) {
                const float a = a4[k], b = prev;
                const float mx = fmaxf(a, b), mn = fminf(a, b);
                const float nv = mx + __logf(1.0f + __expf(mn - mx)) + ee[k];
                prev = a4[k]; a4[k] = nv;
            }
            const int t2 = min(t + 2, nf - 1);
            const float* xr = xb + (size_t)t2 * FF;
            #pragma unroll
            for (int k = 0; k < 4; ++k) ee[k] = xr[li[k]];
        };
        int t = 0;
        while (t < nf) { step(ea, t); ++t; if (t >= nf) break; step(eb, t); ++t; }
        const int idx = num_lens[n] - 1;
        if ((idx >> 2) == l) {
            const int kk = idx & 3;
            float vv = (kk == 0) ? a4[0] : (kk == 1) ? a4[1] : (kk == 2) ? a4[2] : a4[3];
            ws[NB + n] = vv;
        }
    }
}

extern "C" void kernel_launch(void* const* d_in, const int* in_sizes, int n_in,
                              void* d_out, int out_size, void* d_ws, size_t ws_size,
                              hipStream_t stream) {
    const float* x          = (const float*)d_in[0];
    const int*   sup        = (const int*)d_in[1];
    const float* trans      = (const float*)d_in[2];
    const int*   den_labels = (const int*)d_in[3];
    const int*   num_labels = (const int*)d_in[4];
    const int*   num_lens   = (const int*)d_in[5];
    float* out = (float*)d_out;

    const size_t PBYTES = (size_t)NB * DNODES * 32768;              // 8,388,608
    const size_t BBYTES = (size_t)NB * QNODES * 201 * BST * 2;      // 5,763,072
    const size_t SCB    = (size_t)NB * DNODES * 4 * sizeof(float);  // 16,384
    const size_t SOFF   = PBYTES + BBYTES;
    const size_t DOFF   = SOFF + SCB;              // dsc (64 floats)
    const size_t COFF   = DOFF + 256;              // counter
    const size_t NEEDED = COFF + 256;

    if (ws_size >= NEEDED) {
        unsigned*  Pout    = (unsigned*)d_ws;
        _Float16*  Bd      = (_Float16*)((char*)d_ws + PBYTES);
        float*     scales4 = (float*)((char*)d_ws + SOFF);
        float*     dsc     = (float*)((char*)d_ws + DOFF);
        unsigned*  ctr     = (unsigned*)((char*)d_ws + COFF);
        mmi_nodes<<<dim3(NB * DNODES + NB * QNODES), dim3(256), 0, stream>>>(
            x, sup, trans, den_labels, num_labels, Pout, scales4, Bd);
        mmi_chain<<<dim3(2 * NB), dim3(256), 0, stream>>>(
            (const unsigned short*)d_ws, Bd, scales4, num_lens, sup,
            dsc, ctr, out);
    } else {
        float* ws = (float*)d_ws;
        mmi_forward_fb<<<dim3(20), dim3(256), 0, stream>>>(
            x, sup, trans, den_labels, num_labels, num_lens, ws);
        mmi_finalize<<<dim3(1), dim3(64), 0, stream>>>(ws, sup, out);
    }
}